// Round 7
// baseline (164.505 us; speedup 1.0000x reference)
//
#include <hip/hip_runtime.h>
#include <math.h>

// out[b] = (1^T · Π_d C_d · P) · Π_d x[b,d] + bias — per-row scalars commute
// out of the batch-independent matrix chain.
//
// ROUND 14: ONE kernel. Round-6 verified 103.0 us = ~83 us harness fills +
// ~20 us region (fused ~15 + gap ~2 + scale ~1.5 + gap). Kill the second
// dispatch by making the 32 chain blocks the SCALE CREW:
//   row blocks (2048): stream product -> prodbuf -> release per-unit flag.
//     Never wait on anything (no consumer spin — r3's 8192-wave spin = 934us
//     and r5's cg grid.sync = 88us both died of mass same-address polling).
//   chain blocks (32): verified fold -> pE (~6 us, hidden under stream) ->
//     wait own 64 unit flags (wave-0, 1 lane/flag, s_sleep(16) backoff:
//     ~32 polling waves device-wide, bounded traffic) -> write own 64 KB
//     slice of out (32 CUs ~ 2.5 us).
// Acyclic: rows wait on nothing; chain blocks 0..31 trivially resident.
// Poison-safe: MAGIC flags, no memset. __launch_bounds__(256,8) + LDS-staged
// pE/bias keep VGPR <= 64 so row stream holds 32 waves/CU (18 KB LDS ->
// 8 blocks/CU, round-6 verified).
// Row products underflow fp32 to 0 exactly as the reference (absmax 0.0).

#define DFEAT 2048
#define R 16
#define NR2 256               // R*R
#define OUTD 64
#define CHUNK 64              // cores folded per chain block
#define NCHUNK (DFEAT / CHUNK)    // 32 chain blocks
#define MAGIC 0x7E57C0DE

// (Arow · B)[c0..c0+3]: Arow = 16 LDS floats (4x ds_read_b128), B = 16x16
// row-major LDS matrix. All FMA, no barriers. (verbatim)
__device__ __forceinline__ float4 rowmul(const float* Arow, const float* B,
                                         int c0) {
    float4 acc = {0.f, 0.f, 0.f, 0.f};
    const float4* a4 = (const float4*)Arow;
#pragma unroll
    for (int kk = 0; kk < 4; ++kk) {
        const float4 av = a4[kk];
        const float4 b0 = *(const float4*)&B[(4 * kk + 0) * 16 + c0];
        const float4 b1 = *(const float4*)&B[(4 * kk + 1) * 16 + c0];
        const float4 b2 = *(const float4*)&B[(4 * kk + 2) * 16 + c0];
        const float4 b3 = *(const float4*)&B[(4 * kk + 3) * 16 + c0];
        acc.x = fmaf(av.x, b0.x, fmaf(av.y, b1.x, fmaf(av.z, b2.x, fmaf(av.w, b3.x, acc.x))));
        acc.y = fmaf(av.x, b0.y, fmaf(av.y, b1.y, fmaf(av.z, b2.y, fmaf(av.w, b3.y, acc.y))));
        acc.z = fmaf(av.x, b0.z, fmaf(av.y, b1.z, fmaf(av.z, b2.z, fmaf(av.w, b3.z, acc.z))));
        acc.w = fmaf(av.x, b0.w, fmaf(av.y, b1.w, fmaf(av.z, b2.w, fmaf(av.w, b3.w, acc.w))));
    }
    return acc;
}

__global__ __launch_bounds__(256, 8) void mps_one(const float* __restrict__ cores,
                                                  const float* __restrict__ proj,
                                                  const float* __restrict__ x,
                                                  const float* __restrict__ bias,
                                                  float* __restrict__ out,
                                                  float* __restrict__ prodbuf,
                                                  float* __restrict__ partials,
                                                  int* __restrict__ flags,
                                                  int* __restrict__ uflags,
                                                  float* __restrict__ pE,
                                                  int B) {
    // 18 KB unified LDS pool (round-6 verified) -> 8 blocks/CU.
    //   Bb = S[0..2047], Aw = S[2048..4095], F = S[4096..4607]
    //   Pt = S[0..2047] aliases Bb (dead after fold)
    //   scale stage: SpE = S[4096..4159], Sbias = S[4160..4223], E = S[4224]
    __shared__ __align__(16) float S[4608];
    float* Bbase = S;
    float* Abase = S + 2048;
    float* Fbase = S + 4096;
    float* Pt    = S;

    const int tid  = threadIdx.x;
    const int wave = tid >> 6, lane = tid & 63;
    const int bid  = blockIdx.x;
    const int nunits = B >> 2;            // 4 rows per unit
    const int UPC = nunits / NCHUNK;      // units per chain block (64)

    if (bid >= NCHUNK) {
        // ========== row block (one unit): stream product, release flag =====
        const int u = bid - NCHUNK;
        const int row = u * 4 + wave;
        const float4* xr = (const float4*)(x + (size_t)row * DFEAT);
        float prod = 1.f;
#pragma unroll
        for (int it = 0; it < DFEAT / (64 * 4); ++it) {   // 8 iters, 1 KiB/instr
            float4 v = xr[it * 64 + lane];
            prod *= (v.x * v.y) * (v.z * v.w);
        }
#pragma unroll
        for (int off = 32; off > 0; off >>= 1)            // wave-wide product
            prod *= __shfl_xor(prod, off);
        if (lane == 0) prodbuf[row] = prod;
        __syncthreads();                  // all 4 stores drained (vmcnt)
        if (tid == 0)
            __hip_atomic_store(&uflags[u], MAGIC,
                               __ATOMIC_RELEASE, __HIP_MEMORY_SCOPE_AGENT);
        return;
    }

    // ==================== chain block (bid < 32) ===========================
    const int ri = lane >> 2;             // row 0..15 (this lane's A/F row)
    const int c0 = (lane & 3) << 2;       // col base 0,4,8,12
    const size_t d0 = (size_t)bid * CHUNK;

    // ---- per-wave fold of 16 matrices, wave-synchronous (verbatim r6) ----
    const float* gw = cores + (d0 + 16 * wave) * NR2;
    float4 pre[16];
#pragma unroll
    for (int t = 0; t < 16; ++t)
        pre[t] = *(const float4*)&gw[(size_t)t * NR2 + lane * 4];

    float* AwW = Abase + wave * 512;      // this wave's A ping-pong (2x256)
    float* BbW = Bbase + wave * 512;      // this wave's core ping-pong (2x256)

    *(float4*)&AwW[0 * 256 + lane * 4] = pre[0];       // A = core0
    int cur = 0;
#pragma unroll
    for (int t = 1; t < 16; ++t) {        // 15 multiplies -> result in buf 1
        *(float4*)&BbW[(t & 1) * 256 + lane * 4] = pre[t];
        float4 r = rowmul(&AwW[cur * 256 + ri * 16], &BbW[(t & 1) * 256], c0);
        *(float4*)&AwW[(cur ^ 1) * 256 + ri * 16 + c0] = r;
        cur ^= 1;
    }
    __syncthreads();                      // all 4 wave-products ready

    // ---- wave 0 combines: F = Aw0 x Aw1 x Aw2 x Aw3 (3 multiplies) ----
    if (wave == 0) {
        *(float4*)&Fbase[0 * 256 + ri * 16 + c0] =
            *(const float4*)&Abase[0 * 512 + 1 * 256 + ri * 16 + c0];
        int cc = 0;
        for (int w = 1; w < 4; ++w) {
            float4 r = rowmul(&Fbase[cc * 256 + ri * 16],
                              &Abase[w * 512 + 1 * 256], c0);
            *(float4*)&Fbase[(cc ^ 1) * 256 + ri * 16 + c0] = r;
            cc ^= 1;
        }
    }
    __syncthreads();
    const int i = tid >> 4, j = tid & 15;
    const float v = Fbase[1 * 256 + tid]; // element (i,j) of chunk product
    // >>> Bb/Aw dead from here: Pt (alias) may be written (block 0 only).

    if (bid != 0) {
        // ---- producer: publish partial, release flag (verbatim) ----
        partials[bid * NR2 + tid] = v;
        __syncthreads();                  // block stores drained at L2
        if (tid == 0)
            __hip_atomic_store(&flags[bid], MAGIC,
                               __ATOMIC_RELEASE, __HIP_MEMORY_SCOPE_AGENT);
    } else {
        // ---- block 0: own partial straight into LDS slot 0 (transposed) ---
        Pt[0 * 256 + j * 16 + i] = v;

        // acquire-spin for producers 1..31 (verified safe: 4 waves)
        {
            const int f = 1 + (tid % (NCHUNK - 1));
            while (__hip_atomic_load(&flags[f], __ATOMIC_ACQUIRE,
                                     __HIP_MEMORY_SCOPE_AGENT) != MAGIC) { }
        }
        __syncthreads();

        // ---- 4 rounds: stage 8 partials transposed + wave-0 fold ----
        float w = 1.f;
        int E = 0;
        for (int rr = 0; rr < 4; ++rr) {
#pragma unroll
            for (int q = 0; q < 2; ++q) {             // 512 float4 / round
                const int idx = q * 256 + tid;
                const int flat = idx * 4;
                const int s = flat >> 8;              // local slot 0..7
                if (rr > 0 || s > 0) {                // slot 0 of rr=0 = own
                    float4 p4 = ((const float4*)(partials +
                                   (size_t)(8 * rr) * NR2))[idx];
                    const int e = flat & 255;
                    const int k = e >> 4, j0 = e & 15;
                    Pt[s * 256 + (j0 + 0) * 16 + k] = p4.x;
                    Pt[s * 256 + (j0 + 1) * 16 + k] = p4.y;
                    Pt[s * 256 + (j0 + 2) * 16 + k] = p4.z;
                    Pt[s * 256 + (j0 + 3) * 16 + k] = p4.w;
                }
            }
            __syncthreads();
            if (tid < 64) {               // wave-0 register fold, 8 per round
                const int jj = tid & 15, q = tid >> 4;
                for (int s = 0; s < 8; ++s) {
                    const float4 pr =
                        *(const float4*)&Pt[s * 256 + jj * 16 + 4 * q];
                    float sum;
                    sum = __shfl(w, 4 * q + 0) * pr.x;
                    sum = fmaf(__shfl(w, 4 * q + 1), pr.y, sum);
                    sum = fmaf(__shfl(w, 4 * q + 2), pr.z, sum);
                    sum = fmaf(__shfl(w, 4 * q + 3), pr.w, sum);
                    sum += __shfl_xor(sum, 16);
                    sum += __shfl_xor(sum, 32);
                    w = sum;
                }
                float m = fabsf(w);        // exact pow2 renorm, once/round
#pragma unroll
                for (int off = 1; off <= 8; off <<= 1)
                    m = fmaxf(m, __shfl_xor(m, off));
                if (m > 0.f) {
                    int e2 = 0;
                    (void)frexpf(m, &e2);
                    w = ldexpf(w, -e2);
                    E += e2;
                }
            }
            __syncthreads();
        }

        if (tid < 64) {
            float p = 0.f;                // p[o] = sum_k w[k] * proj[k][o]
#pragma unroll
            for (int k = 0; k < R; ++k)
                p = fmaf(__shfl(w, k), proj[k * OUTD + tid], p);
            pE[tid] = p;
            if (tid == 0) ((int*)pE)[OUTD] = E;
        }
        __syncthreads();                  // pE stores drained (vmcnt)
        if (tid == 0)
            __hip_atomic_store(&flags[0], MAGIC,
                               __ATOMIC_RELEASE, __HIP_MEMORY_SCOPE_AGENT);
    }

    // ================== scale crew: wait slice + pE, then write ============
    // wave 0: one lane per unit flag of OUR slice (bounded: 32 waves device-
    // wide, s_sleep backoff). wave 1 lane 0: pE-ready flag.
    if (tid < 64) {
        for (int i2 = tid; i2 < UPC; i2 += 64) {
            while (__hip_atomic_load(&uflags[bid * UPC + i2], __ATOMIC_ACQUIRE,
                                     __HIP_MEMORY_SCOPE_AGENT) != MAGIC)
                __builtin_amdgcn_s_sleep(16);
        }
    } else if (tid == 64) {
        while (__hip_atomic_load(&flags[0], __ATOMIC_ACQUIRE,
                                 __HIP_MEMORY_SCOPE_AGENT) != MAGIC)
            __builtin_amdgcn_s_sleep(16);
    }
    __syncthreads();
    // one-shot acquire per thread: cache-inv so this thread's loads see the
    // released prodbuf/pE (same pattern as the verified partial gather).
    (void)__hip_atomic_load(&flags[0], __ATOMIC_ACQUIRE,
                            __HIP_MEMORY_SCOPE_AGENT);

    // stage pE + bias into LDS (F region is dead now)
    if (tid < 16) {
        ((float4*)&Fbase[0])[tid]  = ((const float4*)pE)[tid];    // SpE
        ((float4*)&Fbase[64])[tid] = ((const float4*)bias)[tid];  // Sbias
    }
    if (tid == 16) ((int*)&Fbase[128])[0] = ((const int*)pE)[OUTD];
    __syncthreads();
    const int   E  = ((const int*)&Fbase[128])[0];
    const float4 pe = ((const float4*)&Fbase[0])[tid & 15];
    const float4 bb = ((const float4*)&Fbase[64])[tid & 15];

    // write our 1/32 slice of out: B/2 float4, lane-coalesced
    const int chunk4 = B * (OUTD / 4) / NCHUNK;       // 4096 at B=8192
    const int base4  = bid * chunk4;
    float4* o4 = (float4*)out;
    for (int q = 0; q < chunk4 / 256; ++q) {          // 16 iters
        const int idx = base4 + q * 256 + tid;
        const float pr = prodbuf[idx >> 4];           // 16 lanes share a row
        float4 r;
        r.x = ldexpf(pe.x * pr, E) + bb.x;
        r.y = ldexpf(pe.y * pr, E) + bb.y;
        r.z = ldexpf(pe.z * pr, E) + bb.z;
        r.w = ldexpf(pe.w * pr, E) + bb.w;
        o4[idx] = r;
    }
}

// ---------------------------------------------------------------------------
extern "C" void kernel_launch(void* const* d_in, const int* in_sizes, int n_in,
                              void* d_out, int out_size, void* d_ws, size_t ws_size,
                              hipStream_t stream) {
    const float* inputs = (const float*)d_in[0];   // (B, 2048) fp32
    const float* cores  = (const float*)d_in[1];   // (2048, 16, 16) fp32
    const float* proj   = (const float*)d_in[2];   // (16, 64) fp32
    const float* bias   = (const float*)d_in[3];   // (64,) fp32
    float* out = (float*)d_out;                    // (B, 64) fp32

    const int B = in_sizes[0] / DFEAT;             // 8192

    // ws layout (16B aligned): prodbuf | partials | pE (64f+E pad) | flags |
    // uflags. All poisoned each replay; MAGIC scheme is poison-safe.
    float* prodbuf  = (float*)d_ws;                // B floats
    float* partials = prodbuf + B;                 // 32*256 floats
    float* pE    = partials + NCHUNK * NR2;        // 64 floats + int E (+pad)
    int*   flags = (int*)(pE + 68);                // 32 ints
    int*   uflags = flags + NCHUNK;                // B/4 ints

    const int nunits = B / 4;                      // 4 rows (waves) per block
    mps_one<<<NCHUNK + nunits, 256, 0, stream>>>(cores, proj, inputs, bias,
                                                 out, prodbuf, partials,
                                                 flags, uflags, pE, B);
}

// Round 8
// 154.907 us; speedup vs baseline: 1.0620x; 1.0620x over previous
//
#include <hip/hip_runtime.h>
#include <math.h>

// out[b] = (1^T · Π_d C_d · P) · Π_d x[b,d] + bias — per-row scalars commute
// out of the batch-independent matrix chain.
//
// ROUND 15: base = VERIFIED round-6 structure (102.96 us). Session law
// (3 strikes: r3 mass-spin 934us, r5 cg-sync 88us, r7 bounded flags 110us):
// same-kernel cross-block producer->consumer handoff is eviction-paced on
// non-coherent XCD L2s — NEVER consume another block's output in-kernel
// (sole exception: the verified 32->1 chain fan-in). Kernel boundary is the
// cheap barrier.
//
// THIS ROUND: self-scaling rows. BW-sharing => every row finishes its 8 KB
// at ~10-11 us, AFTER pE is ready (~6 us). So each row wave makes ONE
// non-blocking acquire peek at flags[0] (no retry — not a spin; ~2048
// one-shot loads total): if MAGIC, scale + write out directly (skip
// prodbuf); else publish prodbuf + pending[row]=MAGIC for the fallback.
// mps_scale degenerates to a skip-scan (~0.3 us). Poison refill each
// replay (observed: 2x256MiB fills) makes pending/flags replay-safe.
// Row products underflow fp32 to 0 exactly as the reference (absmax 0.0).

#define DFEAT 2048
#define R 16
#define NR2 256               // R*R
#define OUTD 64
#define CHUNK 64              // cores folded per chain block
#define NCHUNK (DFEAT / CHUNK)    // 32 chain blocks
#define MAGIC 0x7E57C0DE

// (Arow · B)[c0..c0+3]: Arow = 16 LDS floats (4x ds_read_b128), B = 16x16
// row-major LDS matrix. All FMA, no barriers. (verbatim)
__device__ __forceinline__ float4 rowmul(const float* Arow, const float* B,
                                         int c0) {
    float4 acc = {0.f, 0.f, 0.f, 0.f};
    const float4* a4 = (const float4*)Arow;
#pragma unroll
    for (int kk = 0; kk < 4; ++kk) {
        const float4 av = a4[kk];
        const float4 b0 = *(const float4*)&B[(4 * kk + 0) * 16 + c0];
        const float4 b1 = *(const float4*)&B[(4 * kk + 1) * 16 + c0];
        const float4 b2 = *(const float4*)&B[(4 * kk + 2) * 16 + c0];
        const float4 b3 = *(const float4*)&B[(4 * kk + 3) * 16 + c0];
        acc.x = fmaf(av.x, b0.x, fmaf(av.y, b1.x, fmaf(av.z, b2.x, fmaf(av.w, b3.x, acc.x))));
        acc.y = fmaf(av.x, b0.y, fmaf(av.y, b1.y, fmaf(av.z, b2.y, fmaf(av.w, b3.y, acc.y))));
        acc.z = fmaf(av.x, b0.z, fmaf(av.y, b1.z, fmaf(av.z, b2.z, fmaf(av.w, b3.z, acc.z))));
        acc.w = fmaf(av.x, b0.w, fmaf(av.y, b1.w, fmaf(av.z, b2.w, fmaf(av.w, b3.w, acc.w))));
    }
    return acc;
}

__global__ __launch_bounds__(256) void mps_fused(const float* __restrict__ cores,
                                                 const float* __restrict__ proj,
                                                 const float* __restrict__ x,
                                                 const float* __restrict__ bias,
                                                 float* __restrict__ out,
                                                 float* __restrict__ prodbuf,
                                                 int* __restrict__ pending,
                                                 float* __restrict__ partials,
                                                 int* __restrict__ flags,
                                                 float* __restrict__ pE,
                                                 int B) {
    // 18 KB unified LDS pool -> 8 blocks/CU (round-6 verified).
    //   Bb = S[0..2047], Aw = S[2048..4095], F = S[4096..4607]
    //   Pt = S[0..2047] aliases Bb (dead after fold; lifetimes disjoint)
    __shared__ __align__(16) float S[4608];
    float* Bbase = S;
    float* Abase = S + 2048;
    float* Fbase = S + 4096;
    float* Pt    = S;

    const int tid  = threadIdx.x;
    const int wave = tid >> 6, lane = tid & 63;

    if (blockIdx.x >= NCHUNK) {
        // ============ row block: stream product, peek-once, write ==========
        const int row = (blockIdx.x - NCHUNK) * 4 + wave;
        if (row >= B) return;
        const float4* xr = (const float4*)(x + (size_t)row * DFEAT);
        float prod = 1.f;
#pragma unroll
        for (int it = 0; it < DFEAT / (64 * 4); ++it) {   // 8 iters, 1 KiB/instr
            float4 v = xr[it * 64 + lane];
            prod *= (v.x * v.y) * (v.z * v.w);
        }
#pragma unroll
        for (int off = 32; off > 0; off >>= 1)            // wave-wide product
            prod *= __shfl_xor(prod, off);

        // ONE non-blocking acquire peek (same-address, wave-broadcast; also
        // the cache-invalidate that makes pE readable). NO retry loop.
        const int ready =
            (__hip_atomic_load(&flags[0], __ATOMIC_ACQUIRE,
                               __HIP_MEMORY_SCOPE_AGENT) == MAGIC);
        if (ready) {
            const float pv = pE[lane];                    // lane < 64 == OUTD
            const int   E  = ((const int*)pE)[OUTD];
            out[(size_t)row * OUTD + lane] =
                ldexpf(pv * prod, E) + bias[lane];
        } else if (lane == 0) {
            prodbuf[row] = prod;          // fallback; kernel boundary orders
            pending[row] = MAGIC;
        }
        return;
    }

    // ==================== chain block (blockIdx.x < 32), verbatim r6 =======
    const int ri = lane >> 2;             // row 0..15 (this lane's A/F row)
    const int c0 = (lane & 3) << 2;       // col base 0,4,8,12
    const size_t d0 = (size_t)blockIdx.x * CHUNK;

    const float* gw = cores + (d0 + 16 * wave) * NR2;
    float4 pre[16];
#pragma unroll
    for (int t = 0; t < 16; ++t)
        pre[t] = *(const float4*)&gw[(size_t)t * NR2 + lane * 4];

    float* AwW = Abase + wave * 512;      // this wave's A ping-pong (2x256)
    float* BbW = Bbase + wave * 512;      // this wave's core ping-pong (2x256)

    *(float4*)&AwW[0 * 256 + lane * 4] = pre[0];       // A = core0
    int cur = 0;
#pragma unroll
    for (int t = 1; t < 16; ++t) {        // 15 multiplies -> result in buf 1
        *(float4*)&BbW[(t & 1) * 256 + lane * 4] = pre[t];
        float4 r = rowmul(&AwW[cur * 256 + ri * 16], &BbW[(t & 1) * 256], c0);
        *(float4*)&AwW[(cur ^ 1) * 256 + ri * 16 + c0] = r;
        cur ^= 1;
    }
    __syncthreads();                      // all 4 wave-products ready

    if (wave == 0) {
        *(float4*)&Fbase[0 * 256 + ri * 16 + c0] =
            *(const float4*)&Abase[0 * 512 + 1 * 256 + ri * 16 + c0];
        int cc = 0;
        for (int w = 1; w < 4; ++w) {     // 3 multiplies -> result in F[1]
            float4 r = rowmul(&Fbase[cc * 256 + ri * 16],
                              &Abase[w * 512 + 1 * 256], c0);
            *(float4*)&Fbase[(cc ^ 1) * 256 + ri * 16 + c0] = r;
            cc ^= 1;
        }
    }
    __syncthreads();
    const int i = tid >> 4, j = tid & 15;
    const float v = Fbase[1 * 256 + tid]; // element (i,j) of chunk product
    // >>> Bb/Aw dead from here: Pt (alias) may be written.

    if (blockIdx.x != 0) {
        partials[blockIdx.x * NR2 + tid] = v;
        __syncthreads();                  // block stores complete at L2
        if (tid == 0)
            __hip_atomic_store(&flags[blockIdx.x], MAGIC,
                               __ATOMIC_RELEASE, __HIP_MEMORY_SCOPE_AGENT);
        return;
    }

    // ---- block 0: own partial straight into LDS slot 0 (transposed) ----
    Pt[0 * 256 + j * 16 + i] = v;

    // acquire-spin for producers 1..31 (verified safe: 4 waves, rounds 1-6)
    {
        const int f = 1 + (tid % (NCHUNK - 1));
        while (__hip_atomic_load(&flags[f], __ATOMIC_ACQUIRE,
                                 __HIP_MEMORY_SCOPE_AGENT) != MAGIC) { }
    }
    __syncthreads();

    // ---- 4 rounds: stage 8 partials transposed (8 KB) + wave-0 fold ----
    float w = 1.f;                        // fold state lives in wave-0 regs
    int E = 0;
    for (int rr = 0; rr < 4; ++rr) {
#pragma unroll
        for (int q = 0; q < 2; ++q) {                 // 512 float4 / round
            const int idx = q * 256 + tid;
            const int flat = idx * 4;
            const int s = flat >> 8;                  // local slot 0..7
            if (rr > 0 || s > 0) {                    // slot 0 of rr=0 = own
                float4 p4 =
                    ((const float4*)(partials + (size_t)(8 * rr) * NR2))[idx];
                const int e = flat & 255;
                const int k = e >> 4, j0 = e & 15;    // row k, cols j0..j0+3
                Pt[s * 256 + (j0 + 0) * 16 + k] = p4.x;
                Pt[s * 256 + (j0 + 1) * 16 + k] = p4.y;
                Pt[s * 256 + (j0 + 2) * 16 + k] = p4.z;
                Pt[s * 256 + (j0 + 3) * 16 + k] = p4.w;
            }
        }
        __syncthreads();
        if (tid < 64) {                   // wave-0 register fold, 8 per round
            const int jj = tid & 15, q = tid >> 4;    // lane = jj + 16*q
            for (int s = 0; s < 8; ++s) {
                const float4 pr = *(const float4*)&Pt[s * 256 + jj * 16 + 4 * q];
                float sum;
                sum = __shfl(w, 4 * q + 0) * pr.x;    // w[k] lives at lane k
                sum = fmaf(__shfl(w, 4 * q + 1), pr.y, sum);
                sum = fmaf(__shfl(w, 4 * q + 2), pr.z, sum);
                sum = fmaf(__shfl(w, 4 * q + 3), pr.w, sum);
                sum += __shfl_xor(sum, 16);           // sum the 4 q-groups
                sum += __shfl_xor(sum, 32);           // -> nw[jj], replicated
                w = sum;
            }
            float m = fabsf(w);           // exact pow2 renorm, once/round
#pragma unroll
            for (int off = 1; off <= 8; off <<= 1)
                m = fmaxf(m, __shfl_xor(m, off));
            if (m > 0.f) {
                int e2 = 0;
                (void)frexpf(m, &e2);                 // m = f*2^e, f in [.5,1)
                w = ldexpf(w, -e2);                   // exact rescale
                E += e2;
            }
        }
        __syncthreads();                  // Pt reusable next round
    }

    if (tid < 64) {
        // p[o] = sum_k w[k] * proj[k][o]
        float p = 0.f;
#pragma unroll
        for (int k = 0; k < R; ++k)
            p = fmaf(__shfl(w, k), proj[k * OUTD + tid], p);
        pE[tid] = p;
        if (tid == 0) ((int*)pE)[OUTD] = E;
    }
    __syncthreads();                      // pE stores drained (vmcnt)
    if (tid == 0)
        __hip_atomic_store(&flags[0], MAGIC,
                           __ATOMIC_RELEASE, __HIP_MEMORY_SCOPE_AGENT);
}

// ---------------------------------------------------------------------------
// Fallback epilogue: only rows whose wave missed the peek (pending==MAGIC).
// Usually ~none -> pure skip-scan (~8 KB pending reads).
// ---------------------------------------------------------------------------
__global__ __launch_bounds__(256) void mps_scale(const float* __restrict__ prodbuf,
                                                 const int* __restrict__ pending,
                                                 const float* __restrict__ pE,
                                                 const float* __restrict__ bias,
                                                 float* __restrict__ out,
                                                 int B) {
    const int idx = blockIdx.x * 256 + threadIdx.x;   // float4 index
    const int total4 = B * (OUTD / 4);
    if (idx >= total4) return;
    const int row = idx >> 4;             // 16 float4 per row
    if (pending[row] != MAGIC) return;    // self-scaled (poison) -> skip
    const int c4  = idx & 15;
    const float pr = prodbuf[row];
    const int   E  = ((const int*)pE)[OUTD];
    const float4 pe = ((const float4*)pE)[c4];
    const float4 bb = ((const float4*)bias)[c4];
    float4 r;
    r.x = ldexpf(pe.x * pr, E) + bb.x;
    r.y = ldexpf(pe.y * pr, E) + bb.y;
    r.z = ldexpf(pe.z * pr, E) + bb.z;
    r.w = ldexpf(pe.w * pr, E) + bb.w;
    ((float4*)out)[idx] = r;
}

// ---------------------------------------------------------------------------
extern "C" void kernel_launch(void* const* d_in, const int* in_sizes, int n_in,
                              void* d_out, int out_size, void* d_ws, size_t ws_size,
                              hipStream_t stream) {
    const float* inputs = (const float*)d_in[0];   // (B, 2048) fp32
    const float* cores  = (const float*)d_in[1];   // (2048, 16, 16) fp32
    const float* proj   = (const float*)d_in[2];   // (16, 64) fp32
    const float* bias   = (const float*)d_in[3];   // (64,) fp32
    float* out = (float*)d_out;                    // (B, 64) fp32

    const int B = in_sizes[0] / DFEAT;             // 8192

    // ws layout (16B aligned): prodbuf | partials | pE (64f+E pad) | flags |
    // pending. Poisoned each replay (observed 2x256MiB fills) -> MAGIC
    // scheme replay-safe for both flags and pending.
    float* prodbuf  = (float*)d_ws;                // B floats
    float* partials = prodbuf + B;                 // 32*256 floats
    float* pE    = partials + NCHUNK * NR2;        // 64 floats + int E (+pad)
    int*   flags = (int*)(pE + 68);                // 32 ints
    int*   pending = flags + NCHUNK;               // B ints

    const int rowBlocks = (B + 3) / 4;             // 4 rows (waves) per block
    mps_fused<<<NCHUNK + rowBlocks, 256, 0, stream>>>(cores, proj, inputs,
                                                      bias, out, prodbuf,
                                                      pending, partials,
                                                      flags, pE, B);
    mps_scale<<<(B * 16 + 255) / 256, 256, 0, stream>>>(prodbuf, pending, pE,
                                                        bias, out, B);
}

// Round 9
// 107.409 us; speedup vs baseline: 1.5316x; 1.4422x over previous
//
#include <hip/hip_runtime.h>
#include <math.h>

// out[b] = (1^T · Π_d C_d · P) · Π_d x[b,d] + bias — per-row scalars commute
// out of the batch-independent matrix chain.
//
// ROUND 16: structure B — the only unbanned alternative to round-6's
// verified 102.96 us. Session laws (4 strikes, all counter-verified):
//   r3  8192-wave flag spin            -> 934 us  (VALUBusy 0.2%)
//   r5  cooperative grid.sync          ->  88 us/dispatch (VALUBusy 1%)
//   r7  32 sleeping waves on 2048 flags-> 110 us/dispatch (VALUBusy 1%)
//   r8  ONE acquire peek per row wave  ->  73 us/dispatch (VALUBusy 1.5%)
// => NO agent-scope atomics in any grid-scale path. The kernel boundary is
// the only cheap grid barrier; the 31->1 fan-in inside the 32-block chain
// kernel is the only safe in-kernel handoff (verified rounds 1-6).
//
// Structure: [mps_chain: 32 blocks, fold+fan-in+project -> pE]  (~5 us)
//            [mps_rows: 2048 blocks, stream+scale+write out]    (~11 us)
// pE is visible to mps_rows via the dispatch boundary — zero atomics there.
// Deletes: prodbuf round-trip, scale kernel, one launch gap vs round 6.
// Row products underflow fp32 to 0 exactly as the reference (absmax 0.0).

#define DFEAT 2048
#define R 16
#define NR2 256               // R*R
#define OUTD 64
#define CHUNK 64              // cores folded per chain block
#define NCHUNK (DFEAT / CHUNK)    // 32 chain blocks
#define MAGIC 0x7E57C0DE

// (Arow · B)[c0..c0+3]: Arow = 16 LDS floats (4x ds_read_b128), B = 16x16
// row-major LDS matrix. All FMA, no barriers. (verbatim)
__device__ __forceinline__ float4 rowmul(const float* Arow, const float* B,
                                         int c0) {
    float4 acc = {0.f, 0.f, 0.f, 0.f};
    const float4* a4 = (const float4*)Arow;
#pragma unroll
    for (int kk = 0; kk < 4; ++kk) {
        const float4 av = a4[kk];
        const float4 b0 = *(const float4*)&B[(4 * kk + 0) * 16 + c0];
        const float4 b1 = *(const float4*)&B[(4 * kk + 1) * 16 + c0];
        const float4 b2 = *(const float4*)&B[(4 * kk + 2) * 16 + c0];
        const float4 b3 = *(const float4*)&B[(4 * kk + 3) * 16 + c0];
        acc.x = fmaf(av.x, b0.x, fmaf(av.y, b1.x, fmaf(av.z, b2.x, fmaf(av.w, b3.x, acc.x))));
        acc.y = fmaf(av.x, b0.y, fmaf(av.y, b1.y, fmaf(av.z, b2.y, fmaf(av.w, b3.y, acc.y))));
        acc.z = fmaf(av.x, b0.z, fmaf(av.y, b1.z, fmaf(av.z, b2.z, fmaf(av.w, b3.z, acc.z))));
        acc.w = fmaf(av.x, b0.w, fmaf(av.y, b1.w, fmaf(av.z, b2.w, fmaf(av.w, b3.w, acc.w))));
    }
    return acc;
}

// ---------------------------------------------------------------------------
// Chain kernel: 32 blocks. Verbatim round-6 chain path (pre[16] up-front
// loads, wave-parallel tree fold, 31->1 flag fan-in, block-0 register fold,
// projection -> pE). 18 KB LDS with Pt aliased onto dead fold buffers.
// ---------------------------------------------------------------------------
__global__ __launch_bounds__(256) void mps_chain(const float* __restrict__ cores,
                                                 const float* __restrict__ proj,
                                                 float* __restrict__ partials,
                                                 int* __restrict__ flags,
                                                 float* __restrict__ pE) {
    __shared__ __align__(16) float S[4608];
    float* Bbase = S;
    float* Abase = S + 2048;
    float* Fbase = S + 4096;
    float* Pt    = S;                     // alias: block-0 only, post-fold

    const int tid  = threadIdx.x;
    const int wave = tid >> 6, lane = tid & 63;
    const int ri = lane >> 2;             // row 0..15 (this lane's A/F row)
    const int c0 = (lane & 3) << 2;       // col base 0,4,8,12
    const size_t d0 = (size_t)blockIdx.x * CHUNK;

    // ---- per-wave fold of 16 matrices, wave-synchronous (no barriers) ----
    const float* gw = cores + (d0 + 16 * wave) * NR2;
    float4 pre[16];
#pragma unroll
    for (int t = 0; t < 16; ++t)
        pre[t] = *(const float4*)&gw[(size_t)t * NR2 + lane * 4];

    float* AwW = Abase + wave * 512;      // this wave's A ping-pong (2x256)
    float* BbW = Bbase + wave * 512;      // this wave's core ping-pong (2x256)

    *(float4*)&AwW[0 * 256 + lane * 4] = pre[0];       // A = core0
    int cur = 0;
#pragma unroll
    for (int t = 1; t < 16; ++t) {        // 15 multiplies -> result in buf 1
        *(float4*)&BbW[(t & 1) * 256 + lane * 4] = pre[t];
        float4 r = rowmul(&AwW[cur * 256 + ri * 16], &BbW[(t & 1) * 256], c0);
        *(float4*)&AwW[(cur ^ 1) * 256 + ri * 16 + c0] = r;
        cur ^= 1;
    }
    __syncthreads();                      // all 4 wave-products ready

    // ---- wave 0 combines: F = Aw0 x Aw1 x Aw2 x Aw3 (3 multiplies) ----
    if (wave == 0) {
        *(float4*)&Fbase[0 * 256 + ri * 16 + c0] =
            *(const float4*)&Abase[0 * 512 + 1 * 256 + ri * 16 + c0];
        int cc = 0;
        for (int w = 1; w < 4; ++w) {     // 3 multiplies -> result in F[1]
            float4 r = rowmul(&Fbase[cc * 256 + ri * 16],
                              &Abase[w * 512 + 1 * 256], c0);
            *(float4*)&Fbase[(cc ^ 1) * 256 + ri * 16 + c0] = r;
            cc ^= 1;
        }
    }
    __syncthreads();
    const int i = tid >> 4, j = tid & 15;
    const float v = Fbase[1 * 256 + tid]; // element (i,j) of chunk product
    // >>> Bb/Aw dead from here: Pt (alias) may be written.

    if (blockIdx.x != 0) {
        // ---- producer: publish partial, release flag (verbatim) ----
        partials[blockIdx.x * NR2 + tid] = v;
        __syncthreads();                  // block stores complete at L2
        if (tid == 0)
            __hip_atomic_store(&flags[blockIdx.x], MAGIC,
                               __ATOMIC_RELEASE, __HIP_MEMORY_SCOPE_AGENT);
        return;
    }

    // ---- block 0: own partial straight into LDS slot 0 (transposed) ----
    Pt[0 * 256 + j * 16 + i] = v;

    // acquire-spin for producers 1..31 (verified safe: 4 waves, 31 flags)
    {
        const int f = 1 + (tid % (NCHUNK - 1));
        while (__hip_atomic_load(&flags[f], __ATOMIC_ACQUIRE,
                                 __HIP_MEMORY_SCOPE_AGENT) != MAGIC) { }
    }
    __syncthreads();

    // ---- 4 rounds: stage 8 partials transposed (8 KB) + wave-0 fold ----
    float w = 1.f;                        // fold state lives in wave-0 regs
    int E = 0;
    for (int rr = 0; rr < 4; ++rr) {
#pragma unroll
        for (int q = 0; q < 2; ++q) {                 // 512 float4 / round
            const int idx = q * 256 + tid;
            const int flat = idx * 4;
            const int s = flat >> 8;                  // local slot 0..7
            if (rr > 0 || s > 0) {                    // slot 0 of rr=0 = own
                float4 p4 =
                    ((const float4*)(partials + (size_t)(8 * rr) * NR2))[idx];
                const int e = flat & 255;
                const int k = e >> 4, j0 = e & 15;    // row k, cols j0..j0+3
                Pt[s * 256 + (j0 + 0) * 16 + k] = p4.x;
                Pt[s * 256 + (j0 + 1) * 16 + k] = p4.y;
                Pt[s * 256 + (j0 + 2) * 16 + k] = p4.z;
                Pt[s * 256 + (j0 + 3) * 16 + k] = p4.w;
            }
        }
        __syncthreads();
        if (tid < 64) {                   // wave-0 register fold, 8 per round
            const int jj = tid & 15, q = tid >> 4;    // lane = jj + 16*q
            for (int s = 0; s < 8; ++s) {
                const float4 pr = *(const float4*)&Pt[s * 256 + jj * 16 + 4 * q];
                float sum;
                sum = __shfl(w, 4 * q + 0) * pr.x;    // w[k] lives at lane k
                sum = fmaf(__shfl(w, 4 * q + 1), pr.y, sum);
                sum = fmaf(__shfl(w, 4 * q + 2), pr.z, sum);
                sum = fmaf(__shfl(w, 4 * q + 3), pr.w, sum);
                sum += __shfl_xor(sum, 16);           // sum the 4 q-groups
                sum += __shfl_xor(sum, 32);           // -> nw[jj], replicated
                w = sum;
            }
            float m = fabsf(w);           // exact pow2 renorm, once/round
#pragma unroll
            for (int off = 1; off <= 8; off <<= 1)
                m = fmaxf(m, __shfl_xor(m, off));
            if (m > 0.f) {
                int e2 = 0;
                (void)frexpf(m, &e2);                 // m = f*2^e, f in [.5,1)
                w = ldexpf(w, -e2);                   // exact rescale
                E += e2;
            }
        }
        __syncthreads();                  // Pt reusable next round
    }

    if (tid < 64) {
        // p[o] = sum_k w[k] * proj[k][o]
        float p = 0.f;
#pragma unroll
        for (int k = 0; k < R; ++k)
            p = fmaf(__shfl(w, k), proj[k * OUTD + tid], p);
        pE[tid] = p;
        if (tid == 0) ((int*)pE)[OUTD] = E;
    }
}

// ---------------------------------------------------------------------------
// Rows kernel: one wave per batch row — stream 8 KB, product, scale with pE
// (visible via the dispatch boundary; NO atomics), write out. 2048 blocks.
// ---------------------------------------------------------------------------
__global__ __launch_bounds__(256) void mps_rows(const float* __restrict__ x,
                                                const float* __restrict__ pE,
                                                const float* __restrict__ bias,
                                                float* __restrict__ out,
                                                int B) {
    const int gtid = blockIdx.x * 256 + threadIdx.x;
    const int row  = gtid >> 6;           // wave id == row
    const int lane = threadIdx.x & 63;
    if (row >= B) return;

    const float4* xr = (const float4*)(x + (size_t)row * DFEAT);
    float prod = 1.f;
#pragma unroll
    for (int it = 0; it < DFEAT / (64 * 4); ++it) {   // 8 iters, 1 KiB/instr
        float4 v = xr[it * 64 + lane];
        prod *= (v.x * v.y) * (v.z * v.w);
    }
#pragma unroll
    for (int off = 32; off > 0; off >>= 1)            // wave-wide product
        prod *= __shfl_xor(prod, off);

    const float pv = pE[lane];                        // lane < 64 == OUTD
    const int   E  = ((const int*)pE)[OUTD];
    out[(size_t)row * OUTD + lane] = ldexpf(pv * prod, E) + bias[lane];
}

// ---------------------------------------------------------------------------
extern "C" void kernel_launch(void* const* d_in, const int* in_sizes, int n_in,
                              void* d_out, int out_size, void* d_ws, size_t ws_size,
                              hipStream_t stream) {
    const float* inputs = (const float*)d_in[0];   // (B, 2048) fp32
    const float* cores  = (const float*)d_in[1];   // (2048, 16, 16) fp32
    const float* proj   = (const float*)d_in[2];   // (16, 64) fp32
    const float* bias   = (const float*)d_in[3];   // (64,) fp32
    float* out = (float*)d_out;                    // (B, 64) fp32

    const int B = in_sizes[0] / DFEAT;             // 8192

    // ws layout (16B aligned): partials | pE (64f + int E, pad) | flags
    float* partials = (float*)d_ws;                // 32*256 floats (32 KiB)
    float* pE    = partials + NCHUNK * NR2;        // 64 floats + int E (+pad)
    int*   flags = (int*)(pE + 68);                // 32 ints; harness poison
                                                   // != MAGIC each replay

    mps_chain<<<NCHUNK, 256, 0, stream>>>(cores, proj, partials, flags, pE);
    mps_rows<<<(B * 64 + 255) / 256, 256, 0, stream>>>(inputs, pE, bias,
                                                       out, B);
}

// Round 10
// 104.426 us; speedup vs baseline: 1.5753x; 1.0286x over previous
//
#include <hip/hip_runtime.h>
#include <math.h>

// out[b] = (1^T · Π_d C_d · P) · Π_d x[b,d] + bias — per-row scalars commute
// out of the batch-independent matrix chain.
//
// FINAL (round-6 verified, 102.96 us): best of the fully-enumerated design
// space. Session laws (all counter-verified on gfx950):
//   - Agent-scope atomics in grid-scale paths are catastrophic (coherence
//     storms): r3 mass-spin 934us, r5 cg grid.sync 185us, r7 bounded
//     pollers 164us, r8 single acquire-peek/wave 155us. The ONLY safe
//     in-kernel handoff is the 31->1 chain fan-in (4 spinning waves).
//   - Kernel boundary is the cheap grid barrier; serializing chain before
//     rows (r9, 107.4us) loses the chain-under-stream overlap.
//   - Remaining time: ~82us harness poison fills (2x256MiB @ 6.5TB/s,
//     untouchable) + ~11us compulsory 64MB row stream + ~6us structure.
//
// Structure:
//   mps_fused (32 chain + 2048 row blocks): chain folds 64-core chunks
//     (pre[16] up-front core loads, wave-parallel tree fold, flag fan-in,
//     block-0 register fold -> pE); row blocks stream the compulsory 64 MB,
//     write prod, EXIT (no waits). 18 KB LDS (Pt aliased onto dead fold
//     buffers) -> 8 blocks/CU -> all 2080 blocks co-resident, no tail.
//   mps_scale (512 blocks): out = ldexp(pE[o]*prod[b],E)+bias, one
//     float4/thread, 2 MB coalesced.
// Row products underflow fp32 to 0 exactly as the reference (absmax 0.0).

#define DFEAT 2048
#define R 16
#define NR2 256               // R*R
#define OUTD 64
#define CHUNK 64              // cores folded per chain block
#define NCHUNK (DFEAT / CHUNK)    // 32 chain blocks
#define MAGIC 0x7E57C0DE

// (Arow · B)[c0..c0+3]: Arow = 16 LDS floats (4x ds_read_b128), B = 16x16
// row-major LDS matrix. All FMA, no barriers. (verbatim)
__device__ __forceinline__ float4 rowmul(const float* Arow, const float* B,
                                         int c0) {
    float4 acc = {0.f, 0.f, 0.f, 0.f};
    const float4* a4 = (const float4*)Arow;
#pragma unroll
    for (int kk = 0; kk < 4; ++kk) {
        const float4 av = a4[kk];
        const float4 b0 = *(const float4*)&B[(4 * kk + 0) * 16 + c0];
        const float4 b1 = *(const float4*)&B[(4 * kk + 1) * 16 + c0];
        const float4 b2 = *(const float4*)&B[(4 * kk + 2) * 16 + c0];
        const float4 b3 = *(const float4*)&B[(4 * kk + 3) * 16 + c0];
        acc.x = fmaf(av.x, b0.x, fmaf(av.y, b1.x, fmaf(av.z, b2.x, fmaf(av.w, b3.x, acc.x))));
        acc.y = fmaf(av.x, b0.y, fmaf(av.y, b1.y, fmaf(av.z, b2.y, fmaf(av.w, b3.y, acc.y))));
        acc.z = fmaf(av.x, b0.z, fmaf(av.y, b1.z, fmaf(av.z, b2.z, fmaf(av.w, b3.z, acc.z))));
        acc.w = fmaf(av.x, b0.w, fmaf(av.y, b1.w, fmaf(av.z, b2.w, fmaf(av.w, b3.w, acc.w))));
    }
    return acc;
}

__global__ __launch_bounds__(256) void mps_fused(const float* __restrict__ cores,
                                                 const float* __restrict__ proj,
                                                 const float* __restrict__ x,
                                                 float* __restrict__ prodbuf,
                                                 float* __restrict__ partials,
                                                 int* __restrict__ flags,
                                                 float* __restrict__ pE,
                                                 int B) {
    // 18 KB unified LDS pool -> 8 blocks/CU (wave-limited), 2048 co-resident.
    //   Bb = S[0    .. 2047]  (4 waves x 2 bufs x 256)  — core ping-pong
    //   Aw = S[2048 .. 4095]  (4 waves x 2 bufs x 256)  — A ping-pong
    //   F  = S[4096 .. 4607]  (2 bufs x 256)            — combine ping-pong
    //   Pt = S[0    .. 2047]  ALIASES Bb (dead after fold; lifetimes disjoint)
    __shared__ __align__(16) float S[4608];
    float* Bbase = S;
    float* Abase = S + 2048;
    float* Fbase = S + 4096;
    float* Pt    = S;                     // alias: block-0 only, post-fold

    const int tid  = threadIdx.x;
    const int wave = tid >> 6, lane = tid & 63;

    if (blockIdx.x >= NCHUNK) {
        // ================= row block: streaming product, no waits ==========
        const int row = (blockIdx.x - NCHUNK) * 4 + wave;
        if (row >= B) return;
        const float4* xr = (const float4*)(x + (size_t)row * DFEAT);
        float prod = 1.f;
#pragma unroll
        for (int it = 0; it < DFEAT / (64 * 4); ++it) {   // 8 iters, 1 KiB/instr
            float4 v = xr[it * 64 + lane];
            prod *= (v.x * v.y) * (v.z * v.w);
        }
#pragma unroll
        for (int off = 32; off > 0; off >>= 1)            // wave-wide product
            prod *= __shfl_xor(prod, off);
        if (lane == 0) prodbuf[row] = prod;
        return;
    }

    // ==================== chain block (blockIdx.x < 32) =====================
    const int ri = lane >> 2;             // row 0..15 (this lane's A/F row)
    const int c0 = (lane & 3) << 2;       // col base 0,4,8,12
    const size_t d0 = (size_t)blockIdx.x * CHUNK;

    // ---- per-wave fold of 16 matrices, wave-synchronous (no barriers) ----
    // ALL 16 cores loaded up front into registers (one latency exposure).
    // (lane*4 floats == ri*16 + c0, so the coalesced float4 load per lane
    //  lands exactly at this lane's (ri, c0..c0+3) slot.)
    const float* gw = cores + (d0 + 16 * wave) * NR2;
    float4 pre[16];
#pragma unroll
    for (int t = 0; t < 16; ++t)
        pre[t] = *(const float4*)&gw[(size_t)t * NR2 + lane * 4];

    float* AwW = Abase + wave * 512;      // this wave's A ping-pong (2x256)
    float* BbW = Bbase + wave * 512;      // this wave's core ping-pong (2x256)

    *(float4*)&AwW[0 * 256 + lane * 4] = pre[0];       // A = core0
    int cur = 0;
#pragma unroll
    for (int t = 1; t < 16; ++t) {        // 15 multiplies -> result in buf 1
        *(float4*)&BbW[(t & 1) * 256 + lane * 4] = pre[t];
        float4 r = rowmul(&AwW[cur * 256 + ri * 16], &BbW[(t & 1) * 256], c0);
        *(float4*)&AwW[(cur ^ 1) * 256 + ri * 16 + c0] = r;
        cur ^= 1;
    }
    __syncthreads();                      // all 4 wave-products ready

    // ---- wave 0 combines: F = Aw0 x Aw1 x Aw2 x Aw3 (3 multiplies) ----
    if (wave == 0) {
        *(float4*)&Fbase[0 * 256 + ri * 16 + c0] =
            *(const float4*)&Abase[0 * 512 + 1 * 256 + ri * 16 + c0];
        int cc = 0;
        for (int w = 1; w < 4; ++w) {     // 3 multiplies -> result in F[1]
            float4 r = rowmul(&Fbase[cc * 256 + ri * 16],
                              &Abase[w * 512 + 1 * 256], c0);
            *(float4*)&Fbase[(cc ^ 1) * 256 + ri * 16 + c0] = r;
            cc ^= 1;
        }
    }
    __syncthreads();
    const int i = tid >> 4, j = tid & 15;
    const float v = Fbase[1 * 256 + tid]; // element (i,j) of chunk product
    // >>> Bb/Aw are DEAD from here on: Pt (alias of Bb) may now be written.

    if (blockIdx.x != 0) {
        // ---- producer: publish partial, release flag (verbatim) ----
        partials[blockIdx.x * NR2 + tid] = v;
        __syncthreads();                  // block stores complete at L2
        if (tid == 0)
            __hip_atomic_store(&flags[blockIdx.x], MAGIC,
                               __ATOMIC_RELEASE, __HIP_MEMORY_SCOPE_AGENT);
        return;
    }

    // ---- block 0: own partial straight into LDS slot 0 (transposed) ----
    Pt[0 * 256 + j * 16 + i] = v;

    // acquire-spin for producers 1..31 (every thread: cache-inv side effect)
    // SAFE at this scale: 4 waves spinning, proven rounds 1/2/4/6.
    {
        const int f = 1 + (tid % (NCHUNK - 1));
        while (__hip_atomic_load(&flags[f], __ATOMIC_ACQUIRE,
                                 __HIP_MEMORY_SCOPE_AGENT) != MAGIC) { }
    }
    __syncthreads();

    // ---- 4 rounds: stage 8 partials transposed (8 KB) + wave-0 fold ----
    float w = 1.f;                        // fold state lives in wave-0 regs
    int E = 0;
    for (int rr = 0; rr < 4; ++rr) {
#pragma unroll
        for (int q = 0; q < 2; ++q) {                 // 512 float4 / round
            const int idx = q * 256 + tid;
            const int flat = idx * 4;
            const int s = flat >> 8;                  // local slot 0..7
            if (rr > 0 || s > 0) {                    // slot 0 of rr=0 = own
                float4 p4 =
                    ((const float4*)(partials + (size_t)(8 * rr) * NR2))[idx];
                const int e = flat & 255;
                const int k = e >> 4, j0 = e & 15;    // row k, cols j0..j0+3
                Pt[s * 256 + (j0 + 0) * 16 + k] = p4.x;
                Pt[s * 256 + (j0 + 1) * 16 + k] = p4.y;
                Pt[s * 256 + (j0 + 2) * 16 + k] = p4.z;
                Pt[s * 256 + (j0 + 3) * 16 + k] = p4.w;
            }
        }
        __syncthreads();
        if (tid < 64) {                   // wave-0 register fold, 8 per round
            const int jj = tid & 15, q = tid >> 4;    // lane = jj + 16*q
            for (int s = 0; s < 8; ++s) {
                const float4 pr = *(const float4*)&Pt[s * 256 + jj * 16 + 4 * q];
                float sum;
                sum = __shfl(w, 4 * q + 0) * pr.x;    // w[k] lives at lane k
                sum = fmaf(__shfl(w, 4 * q + 1), pr.y, sum);
                sum = fmaf(__shfl(w, 4 * q + 2), pr.z, sum);
                sum = fmaf(__shfl(w, 4 * q + 3), pr.w, sum);
                sum += __shfl_xor(sum, 16);           // sum the 4 q-groups
                sum += __shfl_xor(sum, 32);           // -> nw[jj], replicated
                w = sum;
            }
            // renorm once per round (global gg = 8*rr+7 -> gg&7==7, as before)
            float m = fabsf(w);
#pragma unroll
            for (int off = 1; off <= 8; off <<= 1)
                m = fmaxf(m, __shfl_xor(m, off));
            if (m > 0.f) {
                int e2 = 0;
                (void)frexpf(m, &e2);                 // m = f*2^e, f in [.5,1)
                w = ldexpf(w, -e2);                   // exact rescale
                E += e2;
            }
        }
        __syncthreads();                  // Pt reusable next round
    }

    if (tid < 64) {
        // p[o] = sum_k w[k] * proj[k][o]
        float p = 0.f;
#pragma unroll
        for (int k = 0; k < R; ++k)
            p = fmaf(__shfl(w, k), proj[k * OUTD + tid], p);
        pE[tid] = p;
        if (tid == 0) ((int*)pE)[OUTD] = E;
    }
}

// ---------------------------------------------------------------------------
// Epilogue: out[b][o] = ldexp(pE[o] * prod[b], E) + bias[o]. 2 MB coalesced,
// one float4 per thread (512 blocks at B=8192).
// ---------------------------------------------------------------------------
__global__ __launch_bounds__(256) void mps_scale(const float* __restrict__ prodbuf,
                                                 const float* __restrict__ pE,
                                                 const float* __restrict__ bias,
                                                 float* __restrict__ out,
                                                 int B) {
    const int idx = blockIdx.x * 256 + threadIdx.x;   // float4 index
    const int total4 = B * (OUTD / 4);
    if (idx >= total4) return;
    const int row = idx >> 4;             // 16 float4 per row
    const int c4  = idx & 15;
    const float pr = prodbuf[row];
    const int   E  = ((const int*)pE)[OUTD];
    const float4 pe = ((const float4*)pE)[c4];
    const float4 bb = ((const float4*)bias)[c4];
    float4 r;
    r.x = ldexpf(pe.x * pr, E) + bb.x;
    r.y = ldexpf(pe.y * pr, E) + bb.y;
    r.z = ldexpf(pe.z * pr, E) + bb.z;
    r.w = ldexpf(pe.w * pr, E) + bb.w;
    ((float4*)out)[idx] = r;
}

// ---------------------------------------------------------------------------
extern "C" void kernel_launch(void* const* d_in, const int* in_sizes, int n_in,
                              void* d_out, int out_size, void* d_ws, size_t ws_size,
                              hipStream_t stream) {
    const float* inputs = (const float*)d_in[0];   // (B, 2048) fp32
    const float* cores  = (const float*)d_in[1];   // (2048, 16, 16) fp32
    const float* proj   = (const float*)d_in[2];   // (16, 64) fp32
    const float* bias   = (const float*)d_in[3];   // (64,) fp32
    float* out = (float*)d_out;                    // (B, 64) fp32

    const int B = in_sizes[0] / DFEAT;             // 8192

    // ws layout (16B aligned): prodbuf | partials | pE (64f + E) | flags
    float* prodbuf  = (float*)d_ws;                // B floats (32 KiB)
    float* partials = prodbuf + B;                 // 32*256 floats (32 KiB)
    float* pE    = partials + NCHUNK * NR2;        // 64 floats + int E (+pad)
    int*   flags = (int*)(pE + 68);                // 32 ints; harness poison
                                                   // != MAGIC each replay

    const int rowBlocks = (B + 3) / 4;             // 4 rows (waves) per block
    mps_fused<<<NCHUNK + rowBlocks, 256, 0, stream>>>(cores, proj, inputs,
                                                      prodbuf, partials, flags,
                                                      pE, B);
    mps_scale<<<(B * 16 + 255) / 256, 256, 0, stream>>>(prodbuf, pE, bias,
                                                        out, B);
}